// Round 1
// baseline (314.597 us; speedup 1.0000x reference)
//
#include <hip/hip_runtime.h>

typedef __attribute__((ext_vector_type(8))) short short8;
typedef __attribute__((ext_vector_type(4))) float f32x4;

#define D_DIM 512
#define Q_DIM 128
#define M_BLK 256   // rows per block (4 waves x 64 rows)
#define RT 4        // 16-row tiles per wave
#define CT 8        // 16-col tiles (128 queries)
#define KSTEP 32

// round-to-nearest-even fp32 -> bf16 (bit pattern in a short)
__device__ inline short f2bf(float f) {
    union { float f; unsigned u; } v; v.f = f;
    unsigned r = v.u + 0x7fffu + ((v.u >> 16) & 1u);
    return (short)(r >> 16);
}

// One block per query: compute norms, threshold-tol, bf16-normalized query,
// and initialize out[q] = -1 (the "-1" of the reference; also makes the
// launch idempotent for graph replay since rank_kernel only atomicAdds).
__global__ __launch_bounds__(256) void prep_kernel(
    const float* __restrict__ qs, const float* __restrict__ ts,
    unsigned short* __restrict__ qn, float* __restrict__ thr_adj,
    int* __restrict__ out)
{
    __shared__ float red[3][4];
    const int qi  = blockIdx.x;
    const int tid = threadIdx.x;
    const float* qrow = qs + qi * D_DIM;
    const float* trow = ts + qi * D_DIM;
    float sq = 0.f, st = 0.f, sqt = 0.f;
    for (int d = tid; d < D_DIM; d += 256) {
        float a = qrow[d], b = trow[d];
        sq += a * a; st += b * b; sqt += a * b;
    }
    #pragma unroll
    for (int off = 32; off > 0; off >>= 1) {
        sq  += __shfl_down(sq, off);
        st  += __shfl_down(st, off);
        sqt += __shfl_down(sqt, off);
    }
    const int wave = tid >> 6, lane = tid & 63;
    if (lane == 0) { red[0][wave] = sq; red[1][wave] = st; red[2][wave] = sqt; }
    __syncthreads();
    sq  = red[0][0] + red[0][1] + red[0][2] + red[0][3];
    st  = red[1][0] + red[1][1] + red[1][2] + red[1][3];
    sqt = red[2][0] + red[2][1] + red[2][2] + red[2][3];
    const float qnorm  = fmaxf(sqrtf(sq), 1e-12f);
    const float tnorm  = fmaxf(sqrtf(st), 1e-12f);
    const float thresh = sqt / (qnorm * tnorm);
    if (tid == 0) {
        // mask = (s >= thr) | (|s - thr| <= atol + rtol*|thr|)  ==  s >= thr - tol
        thr_adj[qi] = thresh - (1e-8f + 1e-5f * fabsf(thresh));
        out[qi] = -1;
    }
    const float inv = 1.0f / qnorm;
    for (int d = tid; d < D_DIM; d += 256) {
        qn[qi * D_DIM + d] = (unsigned short)f2bf(qrow[d] * inv);
    }
}

// sims = data(N x 512) @ qn^T(512 x 128), counted against thr_adj per column.
// Per block: 256 rows, 4 waves, each wave owns 64 rows x all 128 cols.
// A-frag (16x32 bf16): lane l holds A[l&15][ (l>>4)*8 + 0..7 ] -> 8 fp32 loads + cvt.
// B-frag (32x16 bf16): lane l holds B[(l>>4)*8 + 0..7][l&15] = qn[l&15][k..k+7] (contig 16B).
// C/D: col = lane&15, row = (lane>>4)*4 + j   [guide §3, m89-verified]
__global__ __launch_bounds__(256, 2) void rank_kernel(
    const float* __restrict__ data,
    const unsigned short* __restrict__ qn,
    const float* __restrict__ thr_adj,
    int* __restrict__ out, int N)
{
    __shared__ int cnt_lds[Q_DIM];
    const int tid  = threadIdx.x;
    const int wave = tid >> 6, lane = tid & 63;
    const int lr   = lane & 15;   // A row / B col within tile
    const int kgrp = lane >> 4;   // 0..3
    const int koff = kgrp * 8;
    const long row0 = (long)blockIdx.x * M_BLK + wave * 64;

    for (int i = tid; i < Q_DIM; i += 256) cnt_lds[i] = 0;
    __syncthreads();

    f32x4 acc[RT][CT] = {};

    const float* aptr[RT];
    #pragma unroll
    for (int rt = 0; rt < RT; ++rt) {
        long r = row0 + rt * 16 + lr;
        if (r > (long)N - 1) r = (long)N - 1;   // clamp tail loads; masked at count
        aptr[rt] = data + r * D_DIM + koff;
    }
    const unsigned short* bbase = qn + lr * D_DIM + koff;

    #pragma unroll 2
    for (int k = 0; k < D_DIM; k += KSTEP) {
        short8 bfrag[CT];
        #pragma unroll
        for (int c = 0; c < CT; ++c)
            bfrag[c] = *(const short8*)(bbase + c * 16 * D_DIM + k);
        #pragma unroll
        for (int rt = 0; rt < RT; ++rt) {
            const float* p = aptr[rt] + k;
            float4 f0 = *(const float4*)(p);
            float4 f1 = *(const float4*)(p + 4);
            short8 afrag;
            afrag[0] = f2bf(f0.x); afrag[1] = f2bf(f0.y);
            afrag[2] = f2bf(f0.z); afrag[3] = f2bf(f0.w);
            afrag[4] = f2bf(f1.x); afrag[5] = f2bf(f1.y);
            afrag[6] = f2bf(f1.z); afrag[7] = f2bf(f1.w);
            #pragma unroll
            for (int c = 0; c < CT; ++c)
                acc[rt][c] = __builtin_amdgcn_mfma_f32_16x16x32_bf16(
                    afrag, bfrag[c], acc[rt][c], 0, 0, 0);
        }
    }

    // count sims >= thr per column, reduce across the wave's 4 k-groups
    #pragma unroll
    for (int c = 0; c < CT; ++c) {
        const float thr = thr_adj[c * 16 + lr];
        int cnt = 0;
        #pragma unroll
        for (int rt = 0; rt < RT; ++rt) {
            #pragma unroll
            for (int j = 0; j < 4; ++j) {
                long grow = row0 + rt * 16 + kgrp * 4 + j;
                if (grow < (long)N && acc[rt][c][j] >= thr) cnt++;
            }
        }
        cnt += __shfl_xor(cnt, 16);
        cnt += __shfl_xor(cnt, 32);
        if (lane < 16) atomicAdd(&cnt_lds[c * 16 + lr], cnt);
    }
    __syncthreads();
    for (int i = tid; i < Q_DIM; i += 256) {
        atomicAdd(&out[i], cnt_lds[i]);
    }
}

extern "C" void kernel_launch(void* const* d_in, const int* in_sizes, int n_in,
                              void* d_out, int out_size, void* d_ws, size_t ws_size,
                              hipStream_t stream)
{
    const float* data    = (const float*)d_in[0];
    const float* queries = (const float*)d_in[1];
    const float* truths  = (const float*)d_in[2];
    const int N = in_sizes[0] / D_DIM;

    unsigned short* qn  = (unsigned short*)d_ws;
    float*          thr = (float*)((char*)d_ws + (size_t)Q_DIM * D_DIM * sizeof(unsigned short));
    int*            out = (int*)d_out;

    prep_kernel<<<Q_DIM, 256, 0, stream>>>(queries, truths, qn, thr, out);

    const int nblk = (N + M_BLK - 1) / M_BLK;
    rank_kernel<<<nblk, 256, 0, stream>>>(data, qn, thr, out, N);
}

// Round 3
// 291.276 us; speedup vs baseline: 1.0801x; 1.0801x over previous
//
#include <hip/hip_runtime.h>
#include <hip/hip_bf16.h>

typedef __attribute__((ext_vector_type(8))) short short8;
typedef __attribute__((ext_vector_type(4))) float f32x4;
typedef __attribute__((ext_vector_type(4))) unsigned int u32x4;

#define D_DIM 512
#define Q_DIM 128
#define M_BLK 256   // rows per block (4 waves x 64 rows)
#define RT 4        // 16-row tiles per wave
#define CT 8        // 16-col tiles (128 queries)
#define KSTEP 32

// packed fp32x2 -> bf16x2 (RNE) via compiler-generated v_cvt_pk_bf16_f32
__device__ inline unsigned cvtpk2(float a, float b) {
    float2 t; t.x = a; t.y = b;
    __hip_bfloat162 h = __float22bfloat162_rn(t);
    unsigned u;
    __builtin_memcpy(&u, &h, 4);
    return u;
}

// scalar fp32 -> bf16 bits (RNE), used in prep only
__device__ inline unsigned short f2bf(float f) {
    union { float f; unsigned u; } v; v.f = f;
    unsigned r = v.u + 0x7fffu + ((v.u >> 16) & 1u);
    return (unsigned short)(r >> 16);
}

// One block per query: norms, threshold-tol, bf16-normalized query,
// out[q] = -1 init (reference's self-row exclusion; also makes the launch
// idempotent for graph replay since rank_kernel only atomicAdds).
__global__ __launch_bounds__(256) void prep_kernel(
    const float* __restrict__ qs, const float* __restrict__ ts,
    unsigned short* __restrict__ qn, float* __restrict__ thr_adj,
    int* __restrict__ out)
{
    __shared__ float red[3][4];
    const int qi  = blockIdx.x;
    const int tid = threadIdx.x;
    const float* qrow = qs + qi * D_DIM;
    const float* trow = ts + qi * D_DIM;
    float sq = 0.f, st = 0.f, sqt = 0.f;
    for (int d = tid; d < D_DIM; d += 256) {
        float a = qrow[d], b = trow[d];
        sq += a * a; st += b * b; sqt += a * b;
    }
    #pragma unroll
    for (int off = 32; off > 0; off >>= 1) {
        sq  += __shfl_down(sq, off);
        st  += __shfl_down(st, off);
        sqt += __shfl_down(sqt, off);
    }
    const int wave = tid >> 6, lane = tid & 63;
    if (lane == 0) { red[0][wave] = sq; red[1][wave] = st; red[2][wave] = sqt; }
    __syncthreads();
    sq  = red[0][0] + red[0][1] + red[0][2] + red[0][3];
    st  = red[1][0] + red[1][1] + red[1][2] + red[1][3];
    sqt = red[2][0] + red[2][1] + red[2][2] + red[2][3];
    const float qnorm  = fmaxf(sqrtf(sq), 1e-12f);
    const float tnorm  = fmaxf(sqrtf(st), 1e-12f);
    const float thresh = sqt / (qnorm * tnorm);
    if (tid == 0) {
        // mask = (s >= thr) | (|s - thr| <= atol + rtol*|thr|)  ==  s >= thr - tol
        thr_adj[qi] = thresh - (1e-8f + 1e-5f * fabsf(thresh));
        out[qi] = -1;
    }
    const float inv = 1.0f / qnorm;
    for (int d = tid; d < D_DIM; d += 256) {
        qn[qi * D_DIM + d] = f2bf(qrow[d] * inv);
    }
}

// sims = data(N x 512) @ qn^T(512 x 128), counted against thr_adj per column.
// Per block: 256 rows, 4 waves, each wave owns 64 rows x all 128 cols.
// A-frag (16x32 bf16): lane l holds A[l&15][(l>>4)*8 + 0..7] -> 32B fp32 load + cvt_pk.
// B-frag (32x16 bf16): lane l holds B[(l>>4)*8+0..7][l&15] = qn[l&15][k..k+7] (contig 16B).
// C/D: col = lane&15, row = (lane>>4)*4 + j   [guide §3, m89-verified]
__global__ __launch_bounds__(256, 2) void rank_kernel(
    const float* __restrict__ data,
    const unsigned short* __restrict__ qn,
    const float* __restrict__ thr_adj,
    int* __restrict__ out, int N)
{
    __shared__ int cnt_lds[Q_DIM];
    const int tid  = threadIdx.x;
    const int lane = tid & 63;
    const int wave = tid >> 6;
    const int lr   = lane & 15;   // A row / B col within tile
    const int kgrp = lane >> 4;   // 0..3
    const int koff = kgrp * 8;
    const int row0 = blockIdx.x * M_BLK + wave * 64;

    for (int i = tid; i < Q_DIM; i += 256) cnt_lds[i] = 0;
    __syncthreads();

    f32x4 acc[RT][CT] = {};

    const float* aptr[RT];
    #pragma unroll
    for (int rt = 0; rt < RT; ++rt) {
        int r = row0 + rt * 16 + lr;
        if (r > N - 1) r = N - 1;   // clamp tail loads; masked at count
        aptr[rt] = data + (size_t)r * D_DIM + koff;
    }
    const unsigned short* bbase = qn + lr * D_DIM + koff;

    #pragma unroll 4
    for (int k = 0; k < D_DIM; k += KSTEP) {
        short8 bfrag[CT];
        #pragma unroll
        for (int c = 0; c < CT; ++c)
            bfrag[c] = *(const short8*)(bbase + c * 16 * D_DIM + k);
        #pragma unroll
        for (int rt = 0; rt < RT; ++rt) {
            const float* p = aptr[rt] + k;
            float4 f0 = *(const float4*)(p);
            float4 f1 = *(const float4*)(p + 4);
            u32x4 pk;
            pk[0] = cvtpk2(f0.x, f0.y);
            pk[1] = cvtpk2(f0.z, f0.w);
            pk[2] = cvtpk2(f1.x, f1.y);
            pk[3] = cvtpk2(f1.z, f1.w);
            short8 afrag;
            __builtin_memcpy(&afrag, &pk, 16);
            #pragma unroll
            for (int c = 0; c < CT; ++c)
                acc[rt][c] = __builtin_amdgcn_mfma_f32_16x16x32_bf16(
                    afrag, bfrag[c], acc[rt][c], 0, 0, 0);
        }
    }

    // count sims >= thr per column, reduce across the wave's 4 k-groups
    const bool full = (row0 + 64 <= N);
    #pragma unroll
    for (int c = 0; c < CT; ++c) {
        const float thr = thr_adj[c * 16 + lr];
        int cnt = 0;
        if (full) {
            #pragma unroll
            for (int rt = 0; rt < RT; ++rt)
                #pragma unroll
                for (int j = 0; j < 4; ++j)
                    cnt += (acc[rt][c][j] >= thr) ? 1 : 0;
        } else {
            #pragma unroll
            for (int rt = 0; rt < RT; ++rt)
                #pragma unroll
                for (int j = 0; j < 4; ++j) {
                    int grow = row0 + rt * 16 + kgrp * 4 + j;
                    if (grow < N && acc[rt][c][j] >= thr) cnt++;
                }
        }
        cnt += __shfl_xor(cnt, 16);
        cnt += __shfl_xor(cnt, 32);
        if (lane < 16) atomicAdd(&cnt_lds[c * 16 + lr], cnt);
    }
    __syncthreads();
    for (int i = tid; i < Q_DIM; i += 256) {
        atomicAdd(&out[i], cnt_lds[i]);
    }
}

extern "C" void kernel_launch(void* const* d_in, const int* in_sizes, int n_in,
                              void* d_out, int out_size, void* d_ws, size_t ws_size,
                              hipStream_t stream)
{
    const float* data    = (const float*)d_in[0];
    const float* queries = (const float*)d_in[1];
    const float* truths  = (const float*)d_in[2];
    const int N = in_sizes[0] / D_DIM;

    unsigned short* qn  = (unsigned short*)d_ws;
    float*          thr = (float*)((char*)d_ws + (size_t)Q_DIM * D_DIM * sizeof(unsigned short));
    int*            out = (int*)d_out;

    prep_kernel<<<Q_DIM, 256, 0, stream>>>(queries, truths, qn, thr, out);

    const int nblk = (N + M_BLK - 1) / M_BLK;
    rank_kernel<<<nblk, 256, 0, stream>>>(data, qn, thr, out, N);
}